// Round 3
// baseline (184.315 us; speedup 1.0000x reference)
//
#include <hip/hip_runtime.h>
#include <hip/hip_bf16.h>

typedef short short8 __attribute__((ext_vector_type(8)));
typedef short short4v __attribute__((ext_vector_type(4)));
typedef float f32x4 __attribute__((ext_vector_type(4)));
typedef __bf16 bf16x8 __attribute__((ext_vector_type(8)));

#define BM 128
#define BN 128
#define BK 64

// Stage a 128x64 bf16 tile (row-major, leading dim ld) from global into LDS.
// LDS is XOR-swizzled in 16B chunks: lds chunk c holds global
// (row = c>>3, kchunk = (c&7) ^ (row&7)). global_load_lds writes linearly, so
// the swizzle is applied to the global source address (G21).
__device__ __forceinline__ void stage_tile(const __hip_bfloat16* __restrict__ g,
                                           int ld, short* lds, int t) {
    const int w = t >> 6;
    const int lane = t & 63;
#pragma unroll
    for (int i = 0; i < 4; ++i) {
        const int cbase = i * 256 + w * 64;      // wave-uniform chunk base
        const int c = cbase + lane;              // this lane's chunk
        const int row = c >> 3;                  // 8 chunks (of 8 bf16) per row
        const int kc = (c & 7) ^ (row & 7);      // swizzled source k-chunk
        __builtin_amdgcn_global_load_lds((const void*)(g + (long)row * ld + kc * 8),
                                         (void*)(lds + cbase * 8), 16, 0, 0);
    }
}

// C[M,N] = act(A[M,K] * Bt[N,K]^T + bias), bf16 inputs, f32 accum.
// 256 threads = 4 waves as 2x2, each wave owns a 64x64 sub-tile (4x4 frags).
// SWZ: T1 bijective XCD-chunked tile swizzle (requires nwg % 8 == 0).
template <int ACT_TANH, int STORE_BF16, int SWZ>
__global__ __launch_bounds__(256) void gemm_bt_kernel(
    const __hip_bfloat16* __restrict__ A, long sA, int lda,
    const __hip_bfloat16* __restrict__ Bt, long sB, int ldb,
    void* __restrict__ Cptr, long sC, int ldc,
    const float* __restrict__ bias, int K) {
    __shared__ __align__(16) short At[BM * BK];
    __shared__ __align__(16) short Bts[BN * BK];

    int bx = blockIdx.x, by = blockIdx.y, bz = blockIdx.z;
    if (SWZ) {
        const int nx = gridDim.x, ny = gridDim.y;
        const int nwg = nx * ny * gridDim.z;
        const int lin = bx + nx * (by + ny * bz);
        const int swz = (lin & 7) * (nwg >> 3) + (lin >> 3);
        bx = swz % nx;
        const int r = swz / nx;
        by = r % ny;
        bz = r / ny;
    }

    const int t = threadIdx.x;
    const int w = t >> 6, lane = t & 63;
    const int wm = w >> 1, wn = w & 1;
    const int fr = lane & 15, quad = lane >> 4;

    const __hip_bfloat16* Ab = A + bz * sA + (long)by * BM * lda;
    const __hip_bfloat16* Bb = Bt + bz * sB + (long)bx * BN * ldb;

    f32x4 acc[4][4] = {};

    const int nk = K / BK;
    for (int kt = 0; kt < nk; ++kt) {
        if (kt) __syncthreads();
        stage_tile(Ab + kt * BK, lda, At, t);
        stage_tile(Bb + kt * BK, ldb, Bts, t);
        __syncthreads();  // drains vmcnt -> LDS tiles ready
#pragma unroll
        for (int ks = 0; ks < 2; ++ks) {
            bf16x8 af[4], bfv[4];
            const int kc = ks * 4 + quad;  // k-chunk index (k0 = ks*32 + quad*8)
#pragma unroll
            for (int m = 0; m < 4; ++m) {
                const int row = wm * 64 + m * 16 + fr;
                const int chunk = row * 8 + (kc ^ (row & 7));
                af[m] = *(const bf16x8*)(const void*)(At + chunk * 8);
            }
#pragma unroll
            for (int n = 0; n < 4; ++n) {
                const int row = wn * 64 + n * 16 + fr;
                const int chunk = row * 8 + (kc ^ (row & 7));
                bfv[n] = *(const bf16x8*)(const void*)(Bts + chunk * 8);
            }
#pragma unroll
            for (int m = 0; m < 4; ++m)
#pragma unroll
                for (int n = 0; n < 4; ++n)
                    acc[m][n] = __builtin_amdgcn_mfma_f32_16x16x32_bf16(
                        af[m], bfv[n], acc[m][n], 0, 0, 0);
        }
    }

    // epilogue: C/D layout col = lane&15, row = (lane>>4)*4 + j  (m89-verified)
    const long rowBase = (long)by * BM + wm * 64;
    const int colBase = bx * BN + wn * 64;
#pragma unroll
    for (int m = 0; m < 4; ++m) {
#pragma unroll
        for (int n = 0; n < 4; ++n) {
            const int col = colBase + n * 16 + fr;
            const float bv = ACT_TANH ? bias[col] : 0.f;
#pragma unroll
            for (int j = 0; j < 4; ++j) {
                const long row = rowBase + m * 16 + quad * 4 + j;
                float v = acc[m][n][j];
                if (ACT_TANH) v = tanhf(v + bv);
                if (STORE_BF16)
                    ((__hip_bfloat16*)Cptr)[bz * sC + row * ldc + col] =
                        __float2bfloat16(v);
                else
                    ((float*)Cptr)[bz * sC + row * ldc + col] = v;
            }
        }
    }
}

// Fused X-prep v3: per block a 128(t) x 64(h) tile of batch b.
// Phase 1: float4 reads of X, b64 bf16 writes of Xbf, f32 stores to padded LDS.
// Phase 2: transpose-read LDS (2-4 way banks only), b64 bf16 writes of Xt
// with 32 lanes contiguous per h-row (256B chunks).
__global__ __launch_bounds__(256) void prep_x_kernel(const float* __restrict__ X,
                                                     __hip_bfloat16* __restrict__ Xbf,
                                                     __hip_bfloat16* __restrict__ Xt) {
    __shared__ float tile[128][65];
    const int b = blockIdx.z;
    const int h0 = blockIdx.x * 64, t0 = blockIdx.y * 128;
    const int tid = threadIdx.x;
    const int rq = tid >> 4;        // 0..15
    const int c4 = (tid & 15) * 4;  // 0..60 step 4

    const float* Xb = X + ((long)(b * 512 + t0)) * 1024 + h0;
    __hip_bfloat16* Xbfb = Xbf + ((long)(b * 512 + t0)) * 1024 + h0;
#pragma unroll
    for (int p = 0; p < 8; ++p) {
        const int row = p * 16 + rq;  // t within tile
        const float4 v = *(const float4*)(Xb + (long)row * 1024 + c4);
        __hip_bfloat16 tmp[4] __attribute__((aligned(8)));
        tmp[0] = __float2bfloat16(v.x);
        tmp[1] = __float2bfloat16(v.y);
        tmp[2] = __float2bfloat16(v.z);
        tmp[3] = __float2bfloat16(v.w);
        *(short4v*)(void*)(Xbfb + (long)row * 1024 + c4) = *(short4v*)(void*)tmp;
        tile[row][c4 + 0] = v.x;
        tile[row][c4 + 1] = v.y;
        tile[row][c4 + 2] = v.z;
        tile[row][c4 + 3] = v.w;
    }
    __syncthreads();

    // 64 h-rows x 32 t-chunks(4) = 2048 chunks, 8 per thread
    __hip_bfloat16* Xtb = Xt + ((long)(b * 1024 + h0)) * 512 + t0;
#pragma unroll
    for (int p = 0; p < 8; ++p) {
        const int id = p * 256 + tid;
        const int h = id >> 5;    // 0..63
        const int tc = id & 31;   // t = 4*tc
        __hip_bfloat16 tmp[4] __attribute__((aligned(8)));
#pragma unroll
        for (int j = 0; j < 4; ++j) tmp[j] = __float2bfloat16(tile[4 * tc + j][h]);
        *(short4v*)(void*)(Xtb + (long)h * 512 + 4 * tc) = *(short4v*)(void*)tmp;
    }
}

// naive small transpose+convert: in [R][C] f32 -> out [C][R] bf16
__global__ __launch_bounds__(256) void transpose_cvt_kernel(const float* __restrict__ in,
                                                            __hip_bfloat16* __restrict__ out,
                                                            int R, int C) {
    const int o = blockIdx.x * 256 + threadIdx.x;
    if (o >= R * C) return;
    const int c = o / R;
    const int r = o - c * R;
    out[o] = __float2bfloat16(in[(long)r * C + c]);
}

// Fused scores+masked-softmax: per block, 64 query rows x full 512 key cols.
// scores = alpha[64x256] * Ut[512x256]^T, then row softmax with key mask,
// P written directly as bf16. 8 waves; wave w owns cols [w*64, w*64+64).
__global__ __launch_bounds__(512) void score_softmax_kernel(
    const __hip_bfloat16* __restrict__ Aa,  // alpha [32768][256]
    const __hip_bfloat16* __restrict__ Ut,  // [512][256]
    __hip_bfloat16* __restrict__ P,         // [32768][512]
    const int* __restrict__ sen) {
    __shared__ __align__(16) short At[64 * 64];
    __shared__ __align__(16) short Bts[512 * 64];
    __shared__ float red[2][64][9];

    const int t = threadIdx.x;
    const int w = t >> 6, lane = t & 63;
    const int fr = lane & 15, quad = lane >> 4;
    const long row0 = (long)blockIdx.x * 64;
    const __hip_bfloat16* Ab = Aa + row0 * 256;

    f32x4 acc[4][4] = {};

    for (int kt = 0; kt < 4; ++kt) {  // K = 256, BK = 64
        if (kt) __syncthreads();
        {   // stage A: 64x64 tile = 512 chunks, 1 per thread
            const int cb = w * 64;
            const int c = cb + lane;
            const int row = c >> 3, kc = (c & 7) ^ (row & 7);
            __builtin_amdgcn_global_load_lds(
                (const void*)(Ab + (long)row * 256 + kt * 64 + kc * 8),
                (void*)(At + cb * 8), 16, 0, 0);
        }
#pragma unroll
        for (int i = 0; i < 8; ++i) {  // stage B: 512x64 tile = 4096 chunks
            const int cb = i * 512 + w * 64;
            const int c = cb + lane;
            const int row = c >> 3, kc = (c & 7) ^ (row & 7);
            __builtin_amdgcn_global_load_lds(
                (const void*)(Ut + (long)row * 256 + kt * 64 + kc * 8),
                (void*)(Bts + cb * 8), 16, 0, 0);
        }
        __syncthreads();
#pragma unroll
        for (int ks = 0; ks < 2; ++ks) {
            bf16x8 af[4], bfv[4];
            const int kc = ks * 4 + quad;
#pragma unroll
            for (int m = 0; m < 4; ++m) {
                const int row = m * 16 + fr;
                const int chunk = row * 8 + (kc ^ (row & 7));
                af[m] = *(const bf16x8*)(const void*)(At + chunk * 8);
            }
#pragma unroll
            for (int n = 0; n < 4; ++n) {
                const int row = w * 64 + n * 16 + fr;
                const int chunk = row * 8 + (kc ^ (row & 7));
                bfv[n] = *(const bf16x8*)(const void*)(Bts + chunk * 8);
            }
#pragma unroll
            for (int m = 0; m < 4; ++m)
#pragma unroll
                for (int n = 0; n < 4; ++n)
                    acc[m][n] = __builtin_amdgcn_mfma_f32_16x16x32_bf16(
                        af[m], bfv[n], acc[m][n], 0, 0, 0);
        }
    }
    __syncthreads();

    // ---- masked softmax over the 512 cols (acc col = w*64+n*16+fr) ----
    const int L = sen[row0 >> 9];  // block-uniform (8 blocks per batch)
    bool valid[4];
#pragma unroll
    for (int n = 0; n < 4; ++n) valid[n] = (w * 64 + n * 16 + fr) < L;

    // per-row max: local over n, shfl over fr (offsets 1..8 stay in quad group)
    float mx[4][4];
#pragma unroll
    for (int m = 0; m < 4; ++m)
#pragma unroll
        for (int j = 0; j < 4; ++j) {
            float v = -3.0e38f;
#pragma unroll
            for (int n = 0; n < 4; ++n)
                if (valid[n]) v = fmaxf(v, acc[m][n][j]);
#pragma unroll
            for (int off = 8; off >= 1; off >>= 1) v = fmaxf(v, __shfl_xor(v, off, 64));
            mx[m][j] = v;
        }
    if (fr == 0) {
#pragma unroll
        for (int m = 0; m < 4; ++m)
#pragma unroll
            for (int j = 0; j < 4; ++j) red[0][m * 16 + quad * 4 + j][w] = mx[m][j];
    }
    __syncthreads();
    float rmax[4][4];
#pragma unroll
    for (int m = 0; m < 4; ++m)
#pragma unroll
        for (int j = 0; j < 4; ++j) {
            const int row = m * 16 + quad * 4 + j;
            float v = red[0][row][0];
#pragma unroll
            for (int ww = 1; ww < 8; ++ww) v = fmaxf(v, red[0][row][ww]);
            rmax[m][j] = v;
        }

    // exp + per-row sum
    float sum[4][4];
#pragma unroll
    for (int m = 0; m < 4; ++m)
#pragma unroll
        for (int j = 0; j < 4; ++j) {
            float s = 0.f;
#pragma unroll
            for (int n = 0; n < 4; ++n) {
                float e = valid[n] ? __expf(acc[m][n][j] - rmax[m][j]) : 0.f;
                acc[m][n][j] = e;
                s += e;
            }
#pragma unroll
            for (int off = 8; off >= 1; off >>= 1) s += __shfl_xor(s, off, 64);
            sum[m][j] = s;
        }
    if (fr == 0) {
#pragma unroll
        for (int m = 0; m < 4; ++m)
#pragma unroll
            for (int j = 0; j < 4; ++j) red[1][m * 16 + quad * 4 + j][w] = sum[m][j];
    }
    __syncthreads();
#pragma unroll
    for (int m = 0; m < 4; ++m)
#pragma unroll
        for (int j = 0; j < 4; ++j) {
            const int row = m * 16 + quad * 4 + j;
            float s = 0.f;
#pragma unroll
            for (int ww = 0; ww < 8; ++ww) s += red[1][row][ww];
            const float inv = 1.f / s;
#pragma unroll
            for (int n = 0; n < 4; ++n)
                P[(row0 + row) * 512 + w * 64 + n * 16 + fr] =
                    __float2bfloat16(acc[m][n][j] * inv);
        }
}

extern "C" void kernel_launch(void* const* d_in, const int* in_sizes, int n_in,
                              void* d_out, int out_size, void* d_ws, size_t ws_size,
                              hipStream_t stream) {
    const float* X = (const float*)d_in[0];
    const int* sen = (const int*)d_in[1];
    const float* W = (const float*)d_in[2];
    const float* bias = (const float*)d_in[3];
    const float* U = (const float*)d_in[4];
    float* out = (float*)d_out;

    const int B = 64, T = 512, H = 1024, A = 256;
    const long M = (long)B * T;  // 32768

    // workspace: Xt (64Mi) | P (32Mi) | Wt (0.5Mi) | Ut (0.25Mi)
    char* ws = (char*)d_ws;
    __hip_bfloat16* Xt = (__hip_bfloat16*)ws;
    __hip_bfloat16* Pbf = (__hip_bfloat16*)(ws + M * H * 2);
    __hip_bfloat16* Wt = (__hip_bfloat16*)(ws + M * H * 2 + M * T * 2);
    __hip_bfloat16* Ut = (__hip_bfloat16*)((char*)Wt + (long)H * A * 2);

    // d_out doubles as scratch: Xbf bf16 in [0,64Mi), alpha bf16 at [64Mi,80Mi).
    // Both are dead before the final GEMM overwrites d_out with Z.
    __hip_bfloat16* Xbf = (__hip_bfloat16*)d_out;
    __hip_bfloat16* alpha = (__hip_bfloat16*)((char*)d_out + M * H * 2);

    // 1. fused X prep: Xbf (row-major bf16) + Xt (transposed bf16), one X read
    prep_x_kernel<<<dim3(H / 64, T / 128, B), 256, 0, stream>>>(X, Xbf, Xt);
    // 2. W^T [A][H], U^T [T][A]
    transpose_cvt_kernel<<<(H * A) / 256, 256, 0, stream>>>(W, Wt, H, A);
    transpose_cvt_kernel<<<(A * T) / 256, 256, 0, stream>>>(U, Ut, A, T);
    // 3. alpha = tanh(X*W + b)   [32768,256] bf16   (nwg=512, T1 swizzle)
    gemm_bt_kernel<1, 1, 1><<<dim3(A / BN, M / BM, 1), 256, 0, stream>>>(
        Xbf, 0, H, Wt, 0, H, (void*)alpha, 0, A, bias, H);
    // 4+5. P = softmax(alpha * U^T, mask) fused, bf16
    score_softmax_kernel<<<(int)(M / 64), 512, 0, stream>>>(alpha, Ut, Pbf, sen);
    // 6. Z = P * X   (batched over B; Bt = Xt; nwg=2048, T1 swizzle)
    gemm_bt_kernel<0, 0, 1><<<dim3(H / BN, T / BM, B), 256, 0, stream>>>(
        Pbf, (long)T * T, T, Xt, (long)H * T, T, (void*)out, (long)T * H, H,
        nullptr, T);
}

// Round 4
// 165.925 us; speedup vs baseline: 1.1108x; 1.1108x over previous
//
#include <hip/hip_runtime.h>
#include <hip/hip_bf16.h>

typedef short short8 __attribute__((ext_vector_type(8)));
typedef short short4v __attribute__((ext_vector_type(4)));
typedef float f32x4 __attribute__((ext_vector_type(4)));
typedef __bf16 bf16x8 __attribute__((ext_vector_type(8)));

// ---------------- 8-wave single-barrier double-buffered GEMM ----------------
// C[M,N] = act(A[M,K] * Bt[N,K]^T + bias). 512 threads = 8 waves (WR x WC),
// per-wave tile (MR*16) x (NR*16). LDS double-buffered; ONE barrier per
// K-step (T3-minimum): stage next tile -> ds_read cur -> MFMA -> sync.
// 16B-chunk XOR swizzle on LDS (inverse applied to global source, G21).

template <int ROWS>
__device__ __forceinline__ void stage2(const __hip_bfloat16* __restrict__ g,
                                       int ld, short* lds, int t) {
    const int w = t >> 6;
    const int lane = t & 63;
#pragma unroll
    for (int i = 0; i < ROWS / 64; ++i) {    // ROWS*8 chunks / 512 threads
        const int cb = i * 512 + w * 64;     // wave-uniform chunk base
        const int c = cb + lane;
        const int row = c >> 3;
        const int kc = (c & 7) ^ (row & 7);  // swizzled source k-chunk
        __builtin_amdgcn_global_load_lds((const void*)(g + (long)row * ld + kc * 8),
                                         (void*)(lds + cb * 8), 16, 0, 0);
    }
}

template <int BMt, int BNt, int WR, int WC, int ACT_TANH, int STORE_BF16>
__global__ __launch_bounds__(512, 2) void gemm_bt2_kernel(
    const __hip_bfloat16* __restrict__ A, long sA, int lda,
    const __hip_bfloat16* __restrict__ Bt, long sB, int ldb,
    void* __restrict__ Cptr, long sC, int ldc,
    const float* __restrict__ bias, int K) {
    constexpr int MR = BMt / (WR * 16);
    constexpr int NR = BNt / (WC * 16);
    __shared__ __align__(16) short sm[2][(BMt + BNt) * 64];

    // T1 bijective XCD-chunked swizzle (nwg % 8 == 0 for all our grids)
    int bx = blockIdx.x, by = blockIdx.y, bz = blockIdx.z;
    {
        const int nx = gridDim.x, ny = gridDim.y;
        const int nwg = nx * ny * gridDim.z;
        const int lin = bx + nx * (by + ny * bz);
        const int swz = (lin & 7) * (nwg >> 3) + (lin >> 3);
        bx = swz % nx;
        const int r = swz / nx;
        by = r % ny;
        bz = r / ny;
    }

    const int t = threadIdx.x;
    const int w = t >> 6, lane = t & 63;
    const int wm = w / WC, wn = w % WC;
    const int fr = lane & 15, quad = lane >> 4;

    const __hip_bfloat16* Ab = A + bz * sA + (long)by * BMt * lda;
    const __hip_bfloat16* Bb = Bt + bz * sB + (long)bx * BNt * ldb;

    f32x4 acc[MR][NR] = {};

    const int nk = K / 64;
    // prologue: stage tile 0 into buf 0
    stage2<BMt>(Ab, lda, &sm[0][0], t);
    stage2<BNt>(Bb, ldb, &sm[0][BMt * 64], t);
    __syncthreads();  // implies vmcnt(0) drain

    int cur = 0;
    for (int kt = 0; kt < nk; ++kt) {
        if (kt + 1 < nk) {  // issue next-tile loads BEFORE compute
            stage2<BMt>(Ab + (kt + 1) * 64, lda, &sm[cur ^ 1][0], t);
            stage2<BNt>(Bb + (kt + 1) * 64, ldb, &sm[cur ^ 1][BMt * 64], t);
        }
        const short* At = &sm[cur][0];
        const short* Bts = &sm[cur][BMt * 64];
#pragma unroll
        for (int ks = 0; ks < 2; ++ks) {
            bf16x8 af[MR], bfv[NR];
            const int kc = ks * 4 + quad;
#pragma unroll
            for (int m = 0; m < MR; ++m) {
                const int row = wm * (MR * 16) + m * 16 + fr;
                const int chunk = row * 8 + (kc ^ (row & 7));
                af[m] = *(const bf16x8*)(const void*)(At + chunk * 8);
            }
#pragma unroll
            for (int n = 0; n < NR; ++n) {
                const int row = wn * (NR * 16) + n * 16 + fr;
                const int chunk = row * 8 + (kc ^ (row & 7));
                bfv[n] = *(const bf16x8*)(const void*)(Bts + chunk * 8);
            }
#pragma unroll
            for (int m = 0; m < MR; ++m)
#pragma unroll
                for (int n = 0; n < NR; ++n)
                    acc[m][n] = __builtin_amdgcn_mfma_f32_16x16x32_bf16(
                        af[m], bfv[n], acc[m][n], 0, 0, 0);
        }
        if (kt + 1 < nk) __syncthreads();  // stage writes landed; swap
        cur ^= 1;
    }

    // epilogue: C/D layout col = lane&15, row = (lane>>4)*4 + j
    const long rowBase = (long)by * BMt + wm * (MR * 16);
    const int colBase = bx * BNt + wn * (NR * 16);
#pragma unroll
    for (int m = 0; m < MR; ++m) {
#pragma unroll
        for (int n = 0; n < NR; ++n) {
            const int col = colBase + n * 16 + fr;
            const float bv = ACT_TANH ? bias[col] : 0.f;
#pragma unroll
            for (int j = 0; j < 4; ++j) {
                const long row = rowBase + m * 16 + quad * 4 + j;
                float v = acc[m][n][j];
                if (ACT_TANH) v = tanhf(v + bv);
                if (STORE_BF16)
                    ((__hip_bfloat16*)Cptr)[bz * sC + row * ldc + col] =
                        __float2bfloat16(v);
                else
                    ((float*)Cptr)[bz * sC + row * ldc + col] = v;
            }
        }
    }
}

// --------------------------- X prep (v4) -----------------------------------
// Per block: 64(t) x 128(h) tile of batch b. Phase 1: float4 reads, b64 bf16
// Xbf writes, float2 LDS writes. Phase 2: b32 column reads (<=4-way banks),
// b128 Xt writes -- each 16B covers a full 8-t chunk, 128B/row-segment.
__global__ __launch_bounds__(256) void prep_x_kernel(const float* __restrict__ X,
                                                     __hip_bfloat16* __restrict__ Xbf,
                                                     __hip_bfloat16* __restrict__ Xt) {
    __shared__ float tile[64][130];
    const int b = blockIdx.z;
    const int h0 = blockIdx.x * 128, t0 = blockIdx.y * 64;
    const int tid = threadIdx.x;

    const float* Xb = X + ((long)(b * 512 + t0)) * 1024 + h0;
    __hip_bfloat16* Xbfb = Xbf + ((long)(b * 512 + t0)) * 1024 + h0;
#pragma unroll
    for (int p = 0; p < 8; ++p) {
        const int idx = p * 256 + tid;
        const int row = idx >> 5;        // 0..63
        const int c4 = (idx & 31) * 4;   // 0..124
        const float4 v = *(const float4*)(Xb + (long)row * 1024 + c4);
        __hip_bfloat16 tmp[4] __attribute__((aligned(8)));
        tmp[0] = __float2bfloat16(v.x);
        tmp[1] = __float2bfloat16(v.y);
        tmp[2] = __float2bfloat16(v.z);
        tmp[3] = __float2bfloat16(v.w);
        *(short4v*)(void*)(Xbfb + (long)row * 1024 + c4) = *(short4v*)(void*)tmp;
        *(float2*)&tile[row][c4] = make_float2(v.x, v.y);
        *(float2*)&tile[row][c4 + 2] = make_float2(v.z, v.w);
    }
    __syncthreads();

    // 128 h-rows x 8 t-chunks(8) = 1024 chunks of 16B, 4 per thread
    __hip_bfloat16* Xtb = Xt + ((long)(b * 1024 + h0)) * 512 + t0;
#pragma unroll
    for (int p = 0; p < 4; ++p) {
        const int id = p * 256 + tid;
        const int h = id >> 3;    // 0..127
        const int tc = id & 7;    // t = 8*tc + j
        __hip_bfloat16 tmp[8] __attribute__((aligned(16)));
#pragma unroll
        for (int j = 0; j < 8; ++j) tmp[j] = __float2bfloat16(tile[8 * tc + j][h]);
        *(short8*)(void*)(Xtb + (long)h * 512 + 8 * tc) = *(short8*)(void*)tmp;
    }
}

// naive small transpose+convert: in [R][C] f32 -> out [C][R] bf16
__global__ __launch_bounds__(256) void transpose_cvt_kernel(const float* __restrict__ in,
                                                            __hip_bfloat16* __restrict__ out,
                                                            int R, int C) {
    const int o = blockIdx.x * 256 + threadIdx.x;
    if (o >= R * C) return;
    const int c = o / R;
    const int r = o - c * R;
    out[o] = __float2bfloat16(in[(long)r * C + c]);
}

// Fused scores+masked-softmax: per block, 64 query rows x full 512 key cols.
__global__ __launch_bounds__(512) void score_softmax_kernel(
    const __hip_bfloat16* __restrict__ Aa,  // alpha [32768][256]
    const __hip_bfloat16* __restrict__ Ut,  // [512][256]
    __hip_bfloat16* __restrict__ P,         // [32768][512]
    const int* __restrict__ sen) {
    __shared__ __align__(16) short At[64 * 64];
    __shared__ __align__(16) short Bts[512 * 64];
    __shared__ float red[2][64][9];

    const int t = threadIdx.x;
    const int w = t >> 6, lane = t & 63;
    const int fr = lane & 15, quad = lane >> 4;
    const long row0 = (long)blockIdx.x * 64;
    const __hip_bfloat16* Ab = Aa + row0 * 256;

    f32x4 acc[4][4] = {};

    for (int kt = 0; kt < 4; ++kt) {  // K = 256, BK = 64
        if (kt) __syncthreads();
        {   // stage A: 64x64 tile = 512 chunks, 1 per thread
            const int cb = w * 64;
            const int c = cb + lane;
            const int row = c >> 3, kc = (c & 7) ^ (row & 7);
            __builtin_amdgcn_global_load_lds(
                (const void*)(Ab + (long)row * 256 + kt * 64 + kc * 8),
                (void*)(At + cb * 8), 16, 0, 0);
        }
#pragma unroll
        for (int i = 0; i < 8; ++i) {  // stage B: 512x64 tile = 4096 chunks
            const int cb = i * 512 + w * 64;
            const int c = cb + lane;
            const int row = c >> 3, kc = (c & 7) ^ (row & 7);
            __builtin_amdgcn_global_load_lds(
                (const void*)(Ut + (long)row * 256 + kt * 64 + kc * 8),
                (void*)(Bts + cb * 8), 16, 0, 0);
        }
        __syncthreads();
#pragma unroll
        for (int ks = 0; ks < 2; ++ks) {
            bf16x8 af[4], bfv[4];
            const int kc = ks * 4 + quad;
#pragma unroll
            for (int m = 0; m < 4; ++m) {
                const int row = m * 16 + fr;
                const int chunk = row * 8 + (kc ^ (row & 7));
                af[m] = *(const bf16x8*)(const void*)(At + chunk * 8);
            }
#pragma unroll
            for (int n = 0; n < 4; ++n) {
                const int row = w * 64 + n * 16 + fr;
                const int chunk = row * 8 + (kc ^ (row & 7));
                bfv[n] = *(const bf16x8*)(const void*)(Bts + chunk * 8);
            }
#pragma unroll
            for (int m = 0; m < 4; ++m)
#pragma unroll
                for (int n = 0; n < 4; ++n)
                    acc[m][n] = __builtin_amdgcn_mfma_f32_16x16x32_bf16(
                        af[m], bfv[n], acc[m][n], 0, 0, 0);
        }
    }
    __syncthreads();

    // ---- masked softmax over the 512 cols (acc col = w*64+n*16+fr) ----
    const int L = sen[row0 >> 9];
    bool valid[4];
#pragma unroll
    for (int n = 0; n < 4; ++n) valid[n] = (w * 64 + n * 16 + fr) < L;

    float mx[4][4];
#pragma unroll
    for (int m = 0; m < 4; ++m)
#pragma unroll
        for (int j = 0; j < 4; ++j) {
            float v = -3.0e38f;
#pragma unroll
            for (int n = 0; n < 4; ++n)
                if (valid[n]) v = fmaxf(v, acc[m][n][j]);
#pragma unroll
            for (int off = 8; off >= 1; off >>= 1) v = fmaxf(v, __shfl_xor(v, off, 64));
            mx[m][j] = v;
        }
    if (fr == 0) {
#pragma unroll
        for (int m = 0; m < 4; ++m)
#pragma unroll
            for (int j = 0; j < 4; ++j) red[0][m * 16 + quad * 4 + j][w] = mx[m][j];
    }
    __syncthreads();
    float rmax[4][4];
#pragma unroll
    for (int m = 0; m < 4; ++m)
#pragma unroll
        for (int j = 0; j < 4; ++j) {
            const int row = m * 16 + quad * 4 + j;
            float v = red[0][row][0];
#pragma unroll
            for (int ww = 1; ww < 8; ++ww) v = fmaxf(v, red[0][row][ww]);
            rmax[m][j] = v;
        }

    float sum[4][4];
#pragma unroll
    for (int m = 0; m < 4; ++m)
#pragma unroll
        for (int j = 0; j < 4; ++j) {
            float s = 0.f;
#pragma unroll
            for (int n = 0; n < 4; ++n) {
                float e = valid[n] ? __expf(acc[m][n][j] - rmax[m][j]) : 0.f;
                acc[m][n][j] = e;
                s += e;
            }
#pragma unroll
            for (int off = 8; off >= 1; off >>= 1) s += __shfl_xor(s, off, 64);
            sum[m][j] = s;
        }
    if (fr == 0) {
#pragma unroll
        for (int m = 0; m < 4; ++m)
#pragma unroll
            for (int j = 0; j < 4; ++j) red[1][m * 16 + quad * 4 + j][w] = sum[m][j];
    }
    __syncthreads();
#pragma unroll
    for (int m = 0; m < 4; ++m)
#pragma unroll
        for (int j = 0; j < 4; ++j) {
            const int row = m * 16 + quad * 4 + j;
            float s = 0.f;
#pragma unroll
            for (int ww = 0; ww < 8; ++ww) s += red[1][row][ww];
            const float inv = 1.f / s;
#pragma unroll
            for (int n = 0; n < 4; ++n)
                P[(row0 + row) * 512 + w * 64 + n * 16 + fr] =
                    __float2bfloat16(acc[m][n][j] * inv);
        }
}

extern "C" void kernel_launch(void* const* d_in, const int* in_sizes, int n_in,
                              void* d_out, int out_size, void* d_ws, size_t ws_size,
                              hipStream_t stream) {
    const float* X = (const float*)d_in[0];
    const int* sen = (const int*)d_in[1];
    const float* W = (const float*)d_in[2];
    const float* bias = (const float*)d_in[3];
    const float* U = (const float*)d_in[4];
    float* out = (float*)d_out;

    const int B = 64, T = 512, H = 1024, A = 256;
    const long M = (long)B * T;  // 32768

    // workspace: Xt (64Mi) | P (32Mi) | Wt (0.5Mi) | Ut (0.25Mi)
    char* ws = (char*)d_ws;
    __hip_bfloat16* Xt = (__hip_bfloat16*)ws;
    __hip_bfloat16* Pbf = (__hip_bfloat16*)(ws + M * H * 2);
    __hip_bfloat16* Wt = (__hip_bfloat16*)(ws + M * H * 2 + M * T * 2);
    __hip_bfloat16* Ut = (__hip_bfloat16*)((char*)Wt + (long)H * A * 2);

    // d_out doubles as scratch: Xbf bf16 in [0,64Mi), alpha bf16 at [64Mi,80Mi).
    __hip_bfloat16* Xbf = (__hip_bfloat16*)d_out;
    __hip_bfloat16* alpha = (__hip_bfloat16*)((char*)d_out + M * H * 2);

    // 1. fused X prep: Xbf (row-major bf16) + Xt (transposed bf16), one X read
    prep_x_kernel<<<dim3(H / 128, T / 64, B), 256, 0, stream>>>(X, Xbf, Xt);
    // 2. W^T [A][H], U^T [T][A]
    transpose_cvt_kernel<<<(H * A) / 256, 256, 0, stream>>>(W, Wt, H, A);
    transpose_cvt_kernel<<<(A * T) / 256, 256, 0, stream>>>(U, Ut, A, T);
    // 3. alpha = tanh(X*W + b)  [32768,256]  256x128 tile -> 256 wgs (1/CU)
    gemm_bt2_kernel<256, 128, 4, 2, 1, 1><<<dim3(A / 128, (int)(M / 256), 1), 512, 0, stream>>>(
        Xbf, 0, H, Wt, 0, H, (void*)alpha, 0, A, bias, H);
    // 4+5. P = softmax(alpha * U^T, mask) fused, bf16
    score_softmax_kernel<<<(int)(M / 64), 512, 0, stream>>>(alpha, Ut, Pbf, sen);
    // 6. Z = P * X  (batched; Bt = Xt)  256x256 tile -> 512 wgs
    gemm_bt2_kernel<256, 256, 2, 4, 0, 0><<<dim3(H / 256, T / 256, B), 512, 0, stream>>>(
        Pbf, (long)T * T, T, Xt, (long)H * T, T, (void*)out, (long)T * H, H,
        nullptr, T);
}